// Round 1
// baseline (1026.041 us; speedup 1.0000x reference)
//
#include <hip/hip_runtime.h>
#include <hip/hip_bf16.h>

// Problem constants (match reference)
#define T_N   2048
#define E_N   64
#define H_N   1024
#define F_N   512
#define SF_N  2048
#define K_N   6
#define CAP_N 384   // 2 * ceil(T*K / E)

__device__ __forceinline__ float gelu_tanh(float v) {
    float u = 0.7978845608028654f * (v + 0.044715f * v * v * v);
    return 0.5f * v * (1.0f + tanhf(u));
}

// ---------------- router: one wave per token ----------------
__global__ __launch_bounds__(64)
void router_kernel(const float* __restrict__ x, const float* __restrict__ rw,
                   const float* __restrict__ bias,
                   int* __restrict__ top_idx, float* __restrict__ probs) {
    int t = blockIdx.x;
    int lane = threadIdx.x;
    __shared__ float xs[H_N];
    const float* xrow = x + (long)t * H_N;
    #pragma unroll
    for (int i = 0; i < H_N / (64 * 4); ++i) {
        float4 v = *(const float4*)(xrow + (i * 64 + lane) * 4);
        *(float4*)(xs + (i * 64 + lane) * 4) = v;
    }
    __syncthreads();
    // lane = expert index (E_N == 64 == wavefront size)
    const float* wrow = rw + (long)lane * H_N;
    float acc = 0.f;
    for (int h = 0; h < H_N; h += 4) {
        float4 w4 = *(const float4*)(wrow + h);
        acc = fmaf(xs[h + 0], w4.x, acc);
        acc = fmaf(xs[h + 1], w4.y, acc);
        acc = fmaf(xs[h + 2], w4.z, acc);
        acc = fmaf(xs[h + 3], w4.w, acc);
    }
    float score = 1.0f / (1.0f + expf(-acc));
    float b = score + bias[lane];
    float ssum = 0.f;
    int isel[K_N]; float ssel[K_N];
    #pragma unroll
    for (int k = 0; k < K_N; ++k) {
        float m = b;
        #pragma unroll
        for (int off = 32; off > 0; off >>= 1) m = fmaxf(m, __shfl_xor(m, off));
        unsigned long long msk = __ballot(b == m);
        int sel = (int)__builtin_ctzll(msk);   // lowest expert index on ties (matches top_k)
        float sc = __shfl(score, sel);
        isel[k] = sel; ssel[k] = sc; ssum += sc;
        if (lane == sel) b = -INFINITY;
    }
    if (lane == 0) {
        float inv = 1.0f / (ssum + 1e-20f);
        #pragma unroll
        for (int k = 0; k < K_N; ++k) {
            top_idx[t * K_N + k] = isel[k];
            probs[t * K_N + k] = ssel[k] * inv;
        }
    }
}

// ---------------- dispatch: one block per expert, stable scan over pairs ----------------
__global__ __launch_bounds__(256)
void dispatch_kernel(const int* __restrict__ top_idx, int* __restrict__ pair_slot,
                     int* __restrict__ counts, int* __restrict__ tok) {
    int e = blockIdx.x;
    int tid = threadIdx.x;
    int lane = tid & 63, wid = tid >> 6;
    __shared__ int wave_tot[4];
    int base = 0;
    for (int chunk = 0; chunk < (T_N * K_N) / 256; ++chunk) {
        int p = chunk * 256 + tid;
        bool flag = (top_idx[p] == e);
        unsigned long long msk = __ballot(flag);
        int wprefix = __popcll(msk & ((1ull << lane) - 1ull));
        if (lane == 0) wave_tot[wid] = __popcll(msk);
        __syncthreads();
        int pre = 0;
        #pragma unroll
        for (int w = 0; w < 4; ++w) if (w < wid) pre += wave_tot[w];
        int tot = wave_tot[0] + wave_tot[1] + wave_tot[2] + wave_tot[3];
        if (flag) {
            int pos = base + pre + wprefix;
            if (pos < CAP_N) {
                pair_slot[p] = e * CAP_N + pos;
                tok[e * CAP_N + pos] = p / K_N;
            } else {
                pair_slot[p] = -1;   // dropped (over capacity)
            }
        }
        base += tot;
        __syncthreads();
    }
    if (tid == 0) counts[e] = min(base, CAP_N);
}

// ---------------- generic fp32 tiled GEMM ----------------
// C[m][n] = op( sum_k A[m][k] * B[k][n] ), optional gather of A rows, optional
// transposed B (B stored as [n][k]), optional GELU epilogue.
template<bool GATHER, bool BT, bool GELU>
__global__ __launch_bounds__(256)
void gemm_f32(const float* __restrict__ Abase, const float* __restrict__ Bbase,
              float* __restrict__ Cbase,
              int M, int N, int Kd, int lda, int ldb, int ldc,
              long sA, long sB, long sC,
              const int* __restrict__ tok, const int* __restrict__ counts) {
    constexpr int BM = 64, BN = 64, BK = 16;
    int e = blockIdx.z;
    int Me = counts ? min(counts[e], M) : M;
    int m0 = blockIdx.y * BM, n0 = blockIdx.x * BN;
    if (m0 >= Me) return;

    const float* A = Abase + sA * e;
    const float* B = Bbase + sB * e;
    float* C = Cbase + sC * e;

    __shared__ float As[BK][BM];
    __shared__ float Bs[BK][BN];

    int tid = threadIdx.x;
    int tx = tid & 15, ty = tid >> 4;

    // A tile load mapping: row ar (0..63), 4 consecutive k at ac
    int ar = tid >> 2;
    int ac = (tid & 3) << 2;
    int am = m0 + ar;
    bool aok = am < Me;
    const float* arow;
    if (GATHER) {
        int tkn = aok ? tok[e * CAP_N + am] : 0;
        arow = Abase + (long)tkn * lda;
    } else {
        arow = A + (long)(aok ? am : 0) * lda;
    }

    // B tile load mapping
    int br, bc;
    if (!BT) { br = tid >> 4; bc = (tid & 15) << 2; }   // [k][n] rows
    else     { br = tid >> 2; bc = (tid & 3) << 2; }    // [n][k] rows

    float acc[4][4] = {};

    for (int k0 = 0; k0 < Kd; k0 += BK) {
        float4 av = make_float4(0.f, 0.f, 0.f, 0.f);
        if (aok) av = *(const float4*)(arow + k0 + ac);
        float4 bv;
        if (!BT) bv = *(const float4*)(B + (long)(k0 + br) * ldb + n0 + bc);
        else     bv = *(const float4*)(B + (long)(n0 + br) * ldb + k0 + bc);
        __syncthreads();
        As[ac + 0][ar] = av.x;
        As[ac + 1][ar] = av.y;
        As[ac + 2][ar] = av.z;
        As[ac + 3][ar] = av.w;
        if (!BT) {
            *(float4*)&Bs[br][bc] = bv;
        } else {
            Bs[bc + 0][br] = bv.x;
            Bs[bc + 1][br] = bv.y;
            Bs[bc + 2][br] = bv.z;
            Bs[bc + 3][br] = bv.w;
        }
        __syncthreads();
        #pragma unroll
        for (int kk = 0; kk < BK; ++kk) {
            float4 a4 = *(const float4*)&As[kk][ty << 2];
            float4 b4 = *(const float4*)&Bs[kk][tx << 2];
            float a_[4] = {a4.x, a4.y, a4.z, a4.w};
            float b_[4] = {b4.x, b4.y, b4.z, b4.w};
            #pragma unroll
            for (int i = 0; i < 4; ++i)
                #pragma unroll
                for (int j = 0; j < 4; ++j)
                    acc[i][j] = fmaf(a_[i], b_[j], acc[i][j]);
        }
    }

    #pragma unroll
    for (int i = 0; i < 4; ++i) {
        int m = m0 + (ty << 2) + i;
        if (m < Me) {
            float4 o;
            float* ov = &o.x;
            #pragma unroll
            for (int j = 0; j < 4; ++j) {
                float v = acc[i][j];
                if (GELU) v = gelu_tanh(v);
                ov[j] = v;
            }
            *(float4*)(C + (long)m * ldc + n0 + (tx << 2)) = o;
        }
    }
}

// ---------------- combine: out[t] += sum_k prob * y[slot] ----------------
__global__ __launch_bounds__(256)
void combine_kernel(const float* __restrict__ y, const int* __restrict__ pair_slot,
                    const float* __restrict__ probs, float* __restrict__ out) {
    int t = blockIdx.x;
    int tid = threadIdx.x;
    __shared__ int s_slot[K_N];
    __shared__ float s_w[K_N];
    if (tid < K_N) {
        s_slot[tid] = pair_slot[t * K_N + tid];
        s_w[tid] = probs[t * K_N + tid];
    }
    __syncthreads();
    float4 acc = *(float4*)(out + (long)t * H_N + (tid << 2));
    #pragma unroll
    for (int k = 0; k < K_N; ++k) {
        int slot = s_slot[k];
        if (slot >= 0) {
            float w = s_w[k];
            float4 v = *(const float4*)(y + (long)slot * H_N + (tid << 2));
            acc.x = fmaf(w, v.x, acc.x);
            acc.y = fmaf(w, v.y, acc.y);
            acc.z = fmaf(w, v.z, acc.z);
            acc.w = fmaf(w, v.w, acc.w);
        }
    }
    *(float4*)(out + (long)t * H_N + (tid << 2)) = acc;
}

extern "C" void kernel_launch(void* const* d_in, const int* in_sizes, int n_in,
                              void* d_out, int out_size, void* d_ws, size_t ws_size,
                              hipStream_t stream) {
    const float* x    = (const float*)d_in[0];
    const float* rw   = (const float*)d_in[1];
    const float* bias = (const float*)d_in[2];
    const float* w1   = (const float*)d_in[3];
    const float* w2   = (const float*)d_in[4];
    const float* sw1  = (const float*)d_in[5];
    const float* sw2  = (const float*)d_in[6];
    float* out = (float*)d_out;
    char* ws = (char*)d_ws;

    // workspace layout (bytes, 256-aligned)
    int*   top_idx   = (int*)(ws + 0);            // 12288 int
    float* probs     = (float*)(ws + 49152);      // 12288 f32
    int*   pair_slot = (int*)(ws + 98304);        // 12288 int
    int*   counts    = (int*)(ws + 147456);       // 64 int
    int*   tok       = (int*)(ws + 147712);       // E*CAP int
    float* hmid      = (float*)(ws + 246784);     // E*CAP*F f32 = 50331648 B
    float* yb        = (float*)(ws + 50578432);   // E*CAP*H f32 = 100663296 B
    float* smid      = (float*)(ws + 151241728);  // T*SF f32 = 16777216 B
    // total: 168018944 B

    router_kernel<<<T_N, 64, 0, stream>>>(x, rw, bias, top_idx, probs);
    dispatch_kernel<<<E_N, 256, 0, stream>>>(top_idx, pair_slot, counts, tok);

    // shared expert: smid = gelu(x @ sw1^T); out = smid @ sw2^T
    gemm_f32<false, true, true><<<dim3(SF_N / 64, T_N / 64, 1), 256, 0, stream>>>(
        x, sw1, smid, T_N, SF_N, H_N, H_N, H_N, SF_N, 0, 0, 0, nullptr, nullptr);
    gemm_f32<false, true, false><<<dim3(H_N / 64, T_N / 64, 1), 256, 0, stream>>>(
        smid, sw2, out, T_N, H_N, SF_N, SF_N, SF_N, H_N, 0, 0, 0, nullptr, nullptr);

    // expert path: hmid = gelu(gather(x) @ w1[e]); y = hmid @ w2[e]
    gemm_f32<true, false, true><<<dim3(F_N / 64, CAP_N / 64, E_N), 256, 0, stream>>>(
        x, w1, hmid, CAP_N, F_N, H_N, H_N, F_N, F_N,
        0, (long)H_N * F_N, (long)CAP_N * F_N, tok, counts);
    gemm_f32<false, false, false><<<dim3(H_N / 64, CAP_N / 64, E_N), 256, 0, stream>>>(
        hmid, w2, yb, CAP_N, H_N, F_N, F_N, H_N, H_N,
        (long)CAP_N * F_N, (long)F_N * H_N, (long)CAP_N * H_N, nullptr, counts);

    combine_kernel<<<T_N, 256, 0, stream>>>(yb, pair_slot, probs, out);
}

// Round 2
// 595.514 us; speedup vs baseline: 1.7230x; 1.7230x over previous
//
#include <hip/hip_runtime.h>
#include <hip/hip_bf16.h>

// Problem constants (match reference)
#define T_N   2048
#define E_N   64
#define H_N   1024
#define F_N   512
#define SF_N  2048
#define K_N   6
#define CAP_N 384   // 2 * ceil(T*K / E)

typedef __attribute__((ext_vector_type(8))) short short8;   // 8 bf16 (4 VGPRs)
typedef __attribute__((ext_vector_type(4))) float f32x4;    // MFMA accum

__device__ __forceinline__ float gelu_tanh(float v) {
    float u = 0.7978845608028654f * (v + 0.044715f * v * v * v);
    return 0.5f * v * (1.0f + tanhf(u));
}

__device__ __forceinline__ unsigned short f2bf(float v) {
    __hip_bfloat16 h = __float2bfloat16(v);
    return __builtin_bit_cast(unsigned short, h);
}

__device__ __forceinline__ float bf2f(unsigned short u) {
    return __builtin_bit_cast(float, (unsigned)u << 16);
}

// async global->LDS, 16B per lane; LDS dest is wave-uniform base + lane*16
__device__ __forceinline__ void gload_lds16(const void* g, void* l) {
    __builtin_amdgcn_global_load_lds(
        (const __attribute__((address_space(1))) void*)g,
        (__attribute__((address_space(3))) void*)l, 16, 0, 0);
}

// ---------------- fp32 -> bf16 elementwise convert ----------------
__global__ __launch_bounds__(256)
void cvt_f32_bf16(const float* __restrict__ src, unsigned short* __restrict__ dst, int n4) {
    int i = blockIdx.x * 256 + threadIdx.x;
    if (i < n4) {
        float4 v = ((const float4*)src)[i];
        ushort4 o;
        o.x = f2bf(v.x); o.y = f2bf(v.y); o.z = f2bf(v.z); o.w = f2bf(v.w);
        ((ushort4*)dst)[i] = o;
    }
}

// ---------------- per-expert transpose + convert: src f32 [R][C] -> dst bf16 [C][R] ----------------
__global__ __launch_bounds__(256)
void transpose_cvt(const float* __restrict__ src, unsigned short* __restrict__ dst,
                   int R, int C) {
    __shared__ float tile[32][33];
    long eoff = (long)blockIdx.z * R * C;
    int r0 = blockIdx.y * 32, c0 = blockIdx.x * 32;
    int tid = threadIdx.x;
    int tr = tid >> 5, tc = tid & 31;
    #pragma unroll
    for (int i = 0; i < 4; ++i)
        tile[tr + i * 8][tc] = src[eoff + (long)(r0 + tr + i * 8) * C + c0 + tc];
    __syncthreads();
    int wc = tid >> 4, wj = tid & 15;
    #pragma unroll
    for (int i = 0; i < 2; ++i) {
        int c = wc + i * 16;
        ushort2 o;
        o.x = f2bf(tile[2 * wj + 0][c]);
        o.y = f2bf(tile[2 * wj + 1][c]);
        *(ushort2*)&dst[eoff + (long)(c0 + c) * R + r0 + 2 * wj] = o;
    }
}

// ---------------- router: one wave per token (fp32, exact) ----------------
__global__ __launch_bounds__(64)
void router_kernel(const float* __restrict__ x, const float* __restrict__ rw,
                   const float* __restrict__ bias,
                   int* __restrict__ top_idx, float* __restrict__ probs) {
    int t = blockIdx.x;
    int lane = threadIdx.x;
    __shared__ float xs[H_N];
    const float* xrow = x + (long)t * H_N;
    #pragma unroll
    for (int i = 0; i < H_N / (64 * 4); ++i) {
        float4 v = *(const float4*)(xrow + (i * 64 + lane) * 4);
        *(float4*)(xs + (i * 64 + lane) * 4) = v;
    }
    __syncthreads();
    const float* wrow = rw + (long)lane * H_N;
    float acc = 0.f;
    for (int h = 0; h < H_N; h += 4) {
        float4 w4 = *(const float4*)(wrow + h);
        acc = fmaf(xs[h + 0], w4.x, acc);
        acc = fmaf(xs[h + 1], w4.y, acc);
        acc = fmaf(xs[h + 2], w4.z, acc);
        acc = fmaf(xs[h + 3], w4.w, acc);
    }
    float score = 1.0f / (1.0f + expf(-acc));
    float b = score + bias[lane];
    float ssum = 0.f;
    int isel[K_N]; float ssel[K_N];
    #pragma unroll
    for (int k = 0; k < K_N; ++k) {
        float m = b;
        #pragma unroll
        for (int off = 32; off > 0; off >>= 1) m = fmaxf(m, __shfl_xor(m, off));
        unsigned long long msk = __ballot(b == m);
        int sel = (int)__builtin_ctzll(msk);   // lowest index on ties (matches lax.top_k)
        float sc = __shfl(score, sel);
        isel[k] = sel; ssel[k] = sc; ssum += sc;
        if (lane == sel) b = -INFINITY;
    }
    if (lane == 0) {
        float inv = 1.0f / (ssum + 1e-20f);
        #pragma unroll
        for (int k = 0; k < K_N; ++k) {
            top_idx[t * K_N + k] = isel[k];
            probs[t * K_N + k] = ssel[k] * inv;
        }
    }
}

// ---------------- dispatch: one block per expert, stable scan over pairs ----------------
__global__ __launch_bounds__(256)
void dispatch_kernel(const int* __restrict__ top_idx, int* __restrict__ pair_slot,
                     int* __restrict__ counts, int* __restrict__ tok) {
    int e = blockIdx.x;
    int tid = threadIdx.x;
    int lane = tid & 63, wid = tid >> 6;
    // zero-fill tok so unfilled slots gather token 0 (masked at store)
    for (int i = tid; i < CAP_N; i += 256) tok[e * CAP_N + i] = 0;
    __shared__ int wave_tot[4];
    __syncthreads();
    int base = 0;
    for (int chunk = 0; chunk < (T_N * K_N) / 256; ++chunk) {
        int p = chunk * 256 + tid;
        bool flag = (top_idx[p] == e);
        unsigned long long msk = __ballot(flag);
        int wprefix = __popcll(msk & ((1ull << lane) - 1ull));
        if (lane == 0) wave_tot[wid] = __popcll(msk);
        __syncthreads();
        int pre = 0;
        #pragma unroll
        for (int w = 0; w < 4; ++w) if (w < wid) pre += wave_tot[w];
        int tot = wave_tot[0] + wave_tot[1] + wave_tot[2] + wave_tot[3];
        if (flag) {
            int pos = base + pre + wprefix;
            if (pos < CAP_N) {
                pair_slot[p] = e * CAP_N + pos;
                tok[e * CAP_N + pos] = p / K_N;
            } else {
                pair_slot[p] = -1;   // dropped (over capacity)
            }
        }
        base += tot;
        __syncthreads();
    }
    if (tid == 0) counts[e] = min(base, CAP_N);
}

// ---------------- bf16 MFMA GEMM (m97 structure) ----------------
// A [M][K] bf16 row-major (optionally row-gathered via tok), B^T [N][K] bf16,
// C [M][N] (f32 or bf16), optional GELU. 128x128 tile, BK=32, 4 waves.
template<bool GATHER, bool GELU_OUT, bool OUT_BF16>
__global__ __launch_bounds__(256)
void gemm_mfma(const unsigned short* __restrict__ Abase,
               const unsigned short* __restrict__ Bbase,
               void* __restrict__ Cbase,
               int M, int N, int Kd,
               long sA, long sB, long sC,
               const int* __restrict__ tok, const int* __restrict__ counts) {
    __shared__ unsigned short As[128 * 32];
    __shared__ unsigned short Bs[128 * 32];
    int tid = threadIdx.x;
    int w = tid >> 6, l = tid & 63;
    int e = blockIdx.z;
    int Me = counts ? min(counts[e], M) : M;
    int m0 = blockIdx.y * 128, n0 = blockIdx.x * 128;
    if (m0 >= Me) return;

    const unsigned short* Bp = Bbase + sB * e;

    // staging source rows: issue i covers tile rows [i*64, i*64+64)
    const unsigned short* arow0;
    const unsigned short* arow1;
    {
        int r0 = (tid >> 2), r1 = 64 + (tid >> 2);
        if (GATHER) {
            arow0 = Abase + (long)tok[e * CAP_N + m0 + r0] * Kd;
            arow1 = Abase + (long)tok[e * CAP_N + m0 + r1] * Kd;
        } else {
            const unsigned short* Ap = Abase + sA * e;
            arow0 = Ap + (long)(m0 + r0) * Kd;
            arow1 = Ap + (long)(m0 + r1) * Kd;
        }
    }
    const unsigned short* brow0 = Bp + (long)(n0 + (tid >> 2)) * Kd;
    const unsigned short* brow1 = Bp + (long)(n0 + 64 + (tid >> 2)) * Kd;
    int ko = (tid & 3) * 8;

    char* ldsA0 = (char*)As + w * 1024;
    char* ldsA1 = (char*)As + 4096 + w * 1024;
    char* ldsB0 = (char*)Bs + w * 1024;
    char* ldsB1 = (char*)Bs + 4096 + w * 1024;

    int wr = (w >> 1) * 64, wc = (w & 1) * 64;
    int lr = l & 15, lk = (l >> 4) * 8;

    f32x4 acc[4][4] = {};

    for (int k0 = 0; k0 < Kd; k0 += 32) {
        gload_lds16(arow0 + k0 + ko, ldsA0);
        gload_lds16(arow1 + k0 + ko, ldsA1);
        gload_lds16(brow0 + k0 + ko, ldsB0);
        gload_lds16(brow1 + k0 + ko, ldsB1);
        __syncthreads();   // compiler emits vmcnt(0) drain before barrier
        short8 af[4], bfr[4];
        #pragma unroll
        for (int m = 0; m < 4; ++m)
            af[m] = *(const short8*)(As + (wr + m * 16 + lr) * 32 + lk);
        #pragma unroll
        for (int n = 0; n < 4; ++n)
            bfr[n] = *(const short8*)(Bs + (wc + n * 16 + lr) * 32 + lk);
        #pragma unroll
        for (int m = 0; m < 4; ++m)
            #pragma unroll
            for (int n = 0; n < 4; ++n)
                acc[m][n] = __builtin_amdgcn_mfma_f32_16x16x32_bf16(
                    af[m], bfr[n], acc[m][n], 0, 0, 0);
        __syncthreads();
    }

    // epilogue: C/D layout col=lane&15, row=(lane>>4)*4+reg
    int orow = (l >> 4) * 4;
    int ocol = l & 15;
    #pragma unroll
    for (int m = 0; m < 4; ++m) {
        #pragma unroll
        for (int j = 0; j < 4; ++j) {
            int r = m0 + wr + m * 16 + orow + j;
            if (r < Me) {
                #pragma unroll
                for (int n = 0; n < 4; ++n) {
                    float v = acc[m][n][j];
                    if (GELU_OUT) v = gelu_tanh(v);
                    long cidx = sC * e + (long)r * N + n0 + wc + n * 16 + ocol;
                    if (OUT_BF16) ((unsigned short*)Cbase)[cidx] = f2bf(v);
                    else          ((float*)Cbase)[cidx] = v;
                }
            }
        }
    }
}

// ---------------- combine: out[t] += sum_k prob * y[slot] (y bf16) ----------------
__global__ __launch_bounds__(256)
void combine_kernel(const unsigned short* __restrict__ y, const int* __restrict__ pair_slot,
                    const float* __restrict__ probs, float* __restrict__ out) {
    int t = blockIdx.x;
    int tid = threadIdx.x;
    __shared__ int s_slot[K_N];
    __shared__ float s_w[K_N];
    if (tid < K_N) {
        s_slot[tid] = pair_slot[t * K_N + tid];
        s_w[tid] = probs[t * K_N + tid];
    }
    __syncthreads();
    float4 acc = *(float4*)(out + (long)t * H_N + (tid << 2));
    #pragma unroll
    for (int k = 0; k < K_N; ++k) {
        int slot = s_slot[k];
        if (slot >= 0) {
            float wgt = s_w[k];
            ushort4 v = *(const ushort4*)(y + (long)slot * H_N + (tid << 2));
            acc.x = fmaf(wgt, bf2f(v.x), acc.x);
            acc.y = fmaf(wgt, bf2f(v.y), acc.y);
            acc.z = fmaf(wgt, bf2f(v.z), acc.z);
            acc.w = fmaf(wgt, bf2f(v.w), acc.w);
        }
    }
    *(float4*)(out + (long)t * H_N + (tid << 2)) = acc;
}

extern "C" void kernel_launch(void* const* d_in, const int* in_sizes, int n_in,
                              void* d_out, int out_size, void* d_ws, size_t ws_size,
                              hipStream_t stream) {
    const float* x    = (const float*)d_in[0];
    const float* rw   = (const float*)d_in[1];
    const float* bias = (const float*)d_in[2];
    const float* w1   = (const float*)d_in[3];
    const float* w2   = (const float*)d_in[4];
    const float* sw1  = (const float*)d_in[5];
    const float* sw2  = (const float*)d_in[6];
    float* out = (float*)d_out;
    char* ws = (char*)d_ws;

    // workspace layout (bytes, 256-aligned); total ~220 MB
    int*            top_idx   = (int*)(ws + 0);
    float*          probs     = (float*)(ws + 49152);
    int*            pair_slot = (int*)(ws + 98304);
    int*            counts    = (int*)(ws + 147456);
    int*            tok       = (int*)(ws + 147712);
    unsigned short* xb        = (unsigned short*)(ws + 246016);    // T*H bf16
    unsigned short* sw1b      = (unsigned short*)(ws + 4440320);   // SF*H bf16 ([N][K])
    unsigned short* sw2b      = (unsigned short*)(ws + 8634624);   // H*SF bf16 ([N][K])
    unsigned short* w1t       = (unsigned short*)(ws + 12828928);  // E*F*H bf16 ([N][K])
    unsigned short* w2t       = (unsigned short*)(ws + 79937792);  // E*H*F bf16 ([N][K])
    unsigned short* smid      = (unsigned short*)(ws + 147046656); // T*SF bf16
    unsigned short* hmid      = (unsigned short*)(ws + 155435264); // E*CAP*F bf16
    unsigned short* yb        = (unsigned short*)(ws + 180601088); // E*CAP*H bf16

    // ---- convert inputs to bf16 (sw1/sw2 already [N][K]; w1/w2 need transpose) ----
    cvt_f32_bf16<<<2048, 256, 0, stream>>>(x,   xb,   T_N * H_N / 4);
    cvt_f32_bf16<<<2048, 256, 0, stream>>>(sw1, sw1b, SF_N * H_N / 4);
    cvt_f32_bf16<<<2048, 256, 0, stream>>>(sw2, sw2b, H_N * SF_N / 4);
    transpose_cvt<<<dim3(F_N / 32, H_N / 32, E_N), 256, 0, stream>>>(w1, w1t, H_N, F_N);
    transpose_cvt<<<dim3(H_N / 32, F_N / 32, E_N), 256, 0, stream>>>(w2, w2t, F_N, H_N);

    // ---- routing (fp32 exact) ----
    router_kernel<<<T_N, 64, 0, stream>>>(x, rw, bias, top_idx, probs);
    dispatch_kernel<<<E_N, 256, 0, stream>>>(top_idx, pair_slot, counts, tok);

    // ---- shared expert: smid = gelu(x @ sw1^T); out = smid @ sw2^T ----
    gemm_mfma<false, true, true><<<dim3(SF_N / 128, T_N / 128, 1), 256, 0, stream>>>(
        xb, sw1b, smid, T_N, SF_N, H_N, 0, 0, 0, nullptr, nullptr);
    gemm_mfma<false, false, false><<<dim3(H_N / 128, T_N / 128, 1), 256, 0, stream>>>(
        smid, sw2b, out, T_N, H_N, SF_N, 0, 0, 0, nullptr, nullptr);

    // ---- expert path: hmid = gelu(gather(x) @ w1[e]); yb = hmid @ w2[e] ----
    gemm_mfma<true, true, true><<<dim3(F_N / 128, CAP_N / 128, E_N), 256, 0, stream>>>(
        xb, w1t, hmid, CAP_N, F_N, H_N,
        0, (long)F_N * H_N, (long)CAP_N * F_N, tok, counts);
    gemm_mfma<false, false, true><<<dim3(H_N / 128, CAP_N / 128, E_N), 256, 0, stream>>>(
        hmid, w2t, yb, CAP_N, H_N, F_N,
        (long)CAP_N * F_N, (long)H_N * F_N, (long)CAP_N * H_N, nullptr, counts);

    // ---- combine expert outputs into out (which already holds shared path) ----
    combine_kernel<<<T_N, 256, 0, stream>>>(yb, pair_slot, probs, out);
}

// Round 3
// 577.537 us; speedup vs baseline: 1.7766x; 1.0311x over previous
//
#include <hip/hip_runtime.h>
#include <hip/hip_bf16.h>

// Problem constants (match reference)
#define T_N   2048
#define E_N   64
#define H_N   1024
#define F_N   512
#define SF_N  2048
#define K_N   6
#define CAP_N 384   // 2 * ceil(T*K / E)

typedef __attribute__((ext_vector_type(8))) short short8;           // 8 bf16
typedef __attribute__((ext_vector_type(8))) unsigned short u16x8;
typedef __attribute__((ext_vector_type(4))) float f32x4;

__device__ __forceinline__ float gelu_tanh(float v) {
    float u = 0.7978845608028654f * (v + 0.044715f * v * v * v);
    return 0.5f * v * (1.0f + tanhf(u));
}
__device__ __forceinline__ unsigned short f2bf(float v) {
    __hip_bfloat16 h = __float2bfloat16(v);
    return __builtin_bit_cast(unsigned short, h);
}
__device__ __forceinline__ float bf2f(unsigned short u) {
    return __builtin_bit_cast(float, (unsigned)u << 16);
}
__device__ __forceinline__ void gload_lds16(const void* g, void* l) {
    __builtin_amdgcn_global_load_lds(
        (const __attribute__((address_space(1))) void*)g,
        (__attribute__((address_space(3))) void*)l, 16, 0, 0);
}

// ---------------- fused fp32->bf16 convert: x, sw1, sw2 ----------------
__global__ __launch_bounds__(256)
void cvt_all(const float* __restrict__ x, unsigned short* __restrict__ xb,
             const float* __restrict__ sw1, unsigned short* __restrict__ sw1b,
             const float* __restrict__ sw2, unsigned short* __restrict__ sw2b) {
    int i = blockIdx.x * 256 + threadIdx.x;   // 6144 blocks -> 1,572,864 float4s
    const float* s; unsigned short* d; int off;
    if (i < 524288)       { s = x;   d = xb;   off = i; }
    else if (i < 1048576) { s = sw1; d = sw1b; off = i - 524288; }
    else                  { s = sw2; d = sw2b; off = i - 1048576; }
    float4 v = ((const float4*)s)[off];
    ushort4 o;
    o.x = f2bf(v.x); o.y = f2bf(v.y); o.z = f2bf(v.z); o.w = f2bf(v.w);
    ((ushort4*)d)[off] = o;
}

// ---------------- transpose+convert, LDS-free ----------------
// src f32 [R][C] -> dst bf16 [C][R]. Tile: 64 dst-rows (c) x 128 r.
// Reads: lane=c, wave-coalesced 256B per r. Writes: per-lane 64B runs (L2 merges).
__global__ __launch_bounds__(256)
void transpose_cvt2(const float* __restrict__ w1, unsigned short* __restrict__ w1t,
                    const float* __restrict__ w2, unsigned short* __restrict__ w2t) {
    int bid = blockIdx.x;
    const float* src; unsigned short* dst; int R, C, rt, ct;
    if (bid < 4096) {            // w1: R=1024 (8 r-tiles), C=512 (8 c-tiles)
        int e = bid >> 6, t = bid & 63; rt = t >> 3; ct = t & 7; R = 1024; C = 512;
        src = w1 + (long)e * R * C; dst = w1t + (long)e * R * C;
    } else {                     // w2: R=512 (4 r-tiles), C=1024 (16 c-tiles)
        bid -= 4096;
        int e = bid >> 6, t = bid & 63; rt = t >> 4; ct = t & 15; R = 512; C = 1024;
        src = w2 + (long)e * R * C; dst = w2t + (long)e * R * C;
    }
    int tid = threadIdx.x;
    int c = ct * 64 + (tid & 63);
    int rbase = rt * 128 + (tid >> 6) * 32;
    unsigned short buf[32];
    #pragma unroll
    for (int j = 0; j < 32; ++j)
        buf[j] = f2bf(src[(long)(rbase + j) * C + c]);
    #pragma unroll
    for (int j = 0; j < 4; ++j)
        *(u16x8*)(dst + (long)c * R + rbase + j * 8) = *(u16x8*)&buf[j * 8];
}

// ---------------- router: one wave per token (fp32, exact) ----------------
__global__ __launch_bounds__(64)
void router_kernel(const float* __restrict__ x, const float* __restrict__ rw,
                   const float* __restrict__ bias,
                   int* __restrict__ top_idx, float* __restrict__ probs) {
    int t = blockIdx.x;
    int lane = threadIdx.x;
    __shared__ float xs[H_N];
    const float* xrow = x + (long)t * H_N;
    #pragma unroll
    for (int i = 0; i < H_N / (64 * 4); ++i) {
        float4 v = *(const float4*)(xrow + (i * 64 + lane) * 4);
        *(float4*)(xs + (i * 64 + lane) * 4) = v;
    }
    __syncthreads();
    const float* wrow = rw + (long)lane * H_N;
    float acc = 0.f;
    for (int h = 0; h < H_N; h += 4) {
        float4 w4 = *(const float4*)(wrow + h);
        acc = fmaf(xs[h + 0], w4.x, acc);
        acc = fmaf(xs[h + 1], w4.y, acc);
        acc = fmaf(xs[h + 2], w4.z, acc);
        acc = fmaf(xs[h + 3], w4.w, acc);
    }
    float score = 1.0f / (1.0f + expf(-acc));
    float b = score + bias[lane];
    float ssum = 0.f;
    int isel[K_N]; float ssel[K_N];
    #pragma unroll
    for (int k = 0; k < K_N; ++k) {
        float m = b;
        #pragma unroll
        for (int off = 32; off > 0; off >>= 1) m = fmaxf(m, __shfl_xor(m, off));
        unsigned long long msk = __ballot(b == m);
        int sel = (int)__builtin_ctzll(msk);
        float sc = __shfl(score, sel);
        isel[k] = sel; ssel[k] = sc; ssum += sc;
        if (lane == sel) b = -INFINITY;
    }
    if (lane == 0) {
        float inv = 1.0f / (ssum + 1e-20f);
        #pragma unroll
        for (int k = 0; k < K_N; ++k) {
            top_idx[t * K_N + k] = isel[k];
            probs[t * K_N + k] = ssel[k] * inv;
        }
    }
}

// ---------------- dispatch ----------------
__global__ __launch_bounds__(256)
void dispatch_kernel(const int* __restrict__ top_idx, int* __restrict__ pair_slot,
                     int* __restrict__ counts, int* __restrict__ tok) {
    int e = blockIdx.x;
    int tid = threadIdx.x;
    int lane = tid & 63, wid = tid >> 6;
    for (int i = tid; i < CAP_N; i += 256) tok[e * CAP_N + i] = 0;
    __shared__ int wave_tot[4];
    __syncthreads();
    int base = 0;
    for (int chunk = 0; chunk < (T_N * K_N) / 256; ++chunk) {
        int p = chunk * 256 + tid;
        bool flag = (top_idx[p] == e);
        unsigned long long msk = __ballot(flag);
        int wprefix = __popcll(msk & ((1ull << lane) - 1ull));
        if (lane == 0) wave_tot[wid] = __popcll(msk);
        __syncthreads();
        int pre = 0;
        #pragma unroll
        for (int w = 0; w < 4; ++w) if (w < wid) pre += wave_tot[w];
        int tot = wave_tot[0] + wave_tot[1] + wave_tot[2] + wave_tot[3];
        if (flag) {
            int pos = base + pre + wprefix;
            if (pos < CAP_N) {
                pair_slot[p] = e * CAP_N + pos;
                tok[e * CAP_N + pos] = p / K_N;
            } else {
                pair_slot[p] = -1;
            }
        }
        base += tot;
        __syncthreads();
    }
    if (tid == 0) counts[e] = min(base, CAP_N);
}

// ---------------- bf16 MFMA GEMM body: 128x128 tile, BK=64, XOR-swizzled LDS ----------------
// A [*][K] row-major (optional row-gather), B^T [N][K], C [*][N] f32/bf16.
// LDS tiles [128][64] bf16, rows 128B. Slot (r,c) holds global 16B-chunk c^(r&7):
// achieved by pre-swizzling the GLOBAL source k-chunk (linear gload_lds dest),
// un-swizzled on the ds_read side. ds_read_b128 lands 2 lanes/bank (free).
template<bool GELU>
__device__ __forceinline__ void gemm_body(
    const unsigned short* __restrict__ Ag, const unsigned short* __restrict__ Bg,
    void* __restrict__ Cg, bool outbf,
    int N, int Kd, int Me, int m0, int n0,
    const int* __restrict__ tokp,
    unsigned short* As, unsigned short* Bs) {
    int tid = threadIdx.x;
    int w = tid >> 6, l = tid & 63;

    // staging: issue i covers rows i*32 + w*8 + (l>>3); lane's LDS slot = l&7
    int srow = w * 8 + (l >> 3);
    int sko = ((l & 7) ^ (srow & 7)) * 8;   // pre-swizzled global k-chunk (elements)
    const unsigned short* arow[4];
    const unsigned short* brow[4];
    #pragma unroll
    for (int i = 0; i < 4; ++i) {
        int r = i * 32 + srow;
        if (tokp) arow[i] = Ag + (long)tokp[m0 + r] * Kd + sko;
        else      arow[i] = Ag + (long)(m0 + r) * Kd + sko;
        brow[i] = Bg + (long)(n0 + r) * Kd + sko;
    }

    int wr = (w >> 1) * 64, wc = (w & 1) * 64;
    int lr = l & 15;
    // read byte-offset within a 128B row, for k-half h: chunk (h*4 + l>>4) ^ (lr&7)
    int rd0 = (((l >> 4) + 0) ^ (lr & 7)) * 16;
    int rd1 = (((l >> 4) + 4) ^ (lr & 7)) * 16;

    f32x4 acc[4][4] = {};

    for (int k0 = 0; k0 < Kd; k0 += 64) {
        #pragma unroll
        for (int i = 0; i < 4; ++i) {
            gload_lds16(arow[i] + k0, (char*)As + i * 4096 + w * 1024);
            gload_lds16(brow[i] + k0, (char*)Bs + i * 4096 + w * 1024);
        }
        __syncthreads();
        short8 af[4], bf[4];
        #pragma unroll
        for (int m = 0; m < 4; ++m)
            af[m] = *(const short8*)((char*)As + (wr + m * 16 + lr) * 128 + rd0);
        #pragma unroll
        for (int n = 0; n < 4; ++n)
            bf[n] = *(const short8*)((char*)Bs + (wc + n * 16 + lr) * 128 + rd0);
        #pragma unroll
        for (int m = 0; m < 4; ++m)
            #pragma unroll
            for (int n = 0; n < 4; ++n)
                acc[m][n] = __builtin_amdgcn_mfma_f32_16x16x32_bf16(
                    af[m], bf[n], acc[m][n], 0, 0, 0);
        #pragma unroll
        for (int m = 0; m < 4; ++m)
            af[m] = *(const short8*)((char*)As + (wr + m * 16 + lr) * 128 + rd1);
        #pragma unroll
        for (int n = 0; n < 4; ++n)
            bf[n] = *(const short8*)((char*)Bs + (wc + n * 16 + lr) * 128 + rd1);
        #pragma unroll
        for (int m = 0; m < 4; ++m)
            #pragma unroll
            for (int n = 0; n < 4; ++n)
                acc[m][n] = __builtin_amdgcn_mfma_f32_16x16x32_bf16(
                    af[m], bf[n], acc[m][n], 0, 0, 0);
        __syncthreads();
    }

    int orow = (l >> 4) * 4;
    int ocol = l & 15;
    #pragma unroll
    for (int m = 0; m < 4; ++m) {
        #pragma unroll
        for (int j = 0; j < 4; ++j) {
            int r = m0 + wr + m * 16 + orow + j;
            if (r < Me) {
                #pragma unroll
                for (int n = 0; n < 4; ++n) {
                    float v = acc[m][n][j];
                    if (GELU) v = gelu_tanh(v);
                    long cidx = (long)r * N + n0 + wc + n * 16 + ocol;
                    if (outbf) ((unsigned short*)Cg)[cidx] = f2bf(v);
                    else       ((float*)Cg)[cidx] = v;
                }
            }
        }
    }
}

// ---------------- dual GEMM launches (expert + shared co-scheduled) ----------------
__global__ __launch_bounds__(256)
void gemmA(const unsigned short* __restrict__ xb, const unsigned short* __restrict__ w1t,
           unsigned short* __restrict__ hmid,
           const unsigned short* __restrict__ sw1b, unsigned short* __restrict__ smid,
           const int* __restrict__ tok, const int* __restrict__ counts) {
    __shared__ unsigned short As[128 * 64];
    __shared__ unsigned short Bs[128 * 64];
    int bid = blockIdx.x;
    if (bid < 768) {           // expert GEMM1: gather(x) @ w1[e]  (CAP x 512, K=1024)
        int e = bid / 12, r = bid % 12;
        int m0 = (r >> 2) * 128, n0 = (r & 3) * 128;
        int Me = min(counts[e], CAP_N);
        if (m0 >= Me) return;
        gemm_body<true>(xb, w1t + (long)e * F_N * H_N, hmid + (long)e * CAP_N * F_N,
                        true, F_N, H_N, Me, m0, n0, tok + e * CAP_N, As, Bs);
    } else {                   // shared GEMM1: x @ sw1^T  (2048 x 2048, K=1024)
        int sid = bid - 768;
        int m0 = (sid >> 4) * 128, n0 = (sid & 15) * 128;
        gemm_body<true>(xb, sw1b, smid, true, SF_N, H_N, T_N, m0, n0, nullptr, As, Bs);
    }
}

__global__ __launch_bounds__(256)
void gemmB(const unsigned short* __restrict__ hmid, const unsigned short* __restrict__ w2t,
           unsigned short* __restrict__ yb,
           const unsigned short* __restrict__ smid, const unsigned short* __restrict__ sw2b,
           float* __restrict__ out, const int* __restrict__ counts) {
    __shared__ unsigned short As[128 * 64];
    __shared__ unsigned short Bs[128 * 64];
    int bid = blockIdx.x;
    if (bid < 1536) {          // expert GEMM2: hmid @ w2[e]  (CAP x 1024, K=512)
        int e = bid / 24, r = bid % 24;
        int m0 = (r >> 3) * 128, n0 = (r & 7) * 128;
        int Me = min(counts[e], CAP_N);
        if (m0 >= Me) return;
        gemm_body<false>(hmid + (long)e * CAP_N * F_N, w2t + (long)e * H_N * F_N,
                         yb + (long)e * CAP_N * H_N, true, H_N, F_N, Me, m0, n0,
                         nullptr, As, Bs);
    } else {                   // shared GEMM2: smid @ sw2^T -> out fp32 (2048x1024, K=2048)
        int sid = bid - 1536;
        int m0 = (sid >> 3) * 128, n0 = (sid & 7) * 128;
        gemm_body<false>(smid, sw2b, out, false, H_N, SF_N, T_N, m0, n0, nullptr, As, Bs);
    }
}

// ---------------- combine ----------------
__global__ __launch_bounds__(256)
void combine_kernel(const unsigned short* __restrict__ y, const int* __restrict__ pair_slot,
                    const float* __restrict__ probs, float* __restrict__ out) {
    int t = blockIdx.x;
    int tid = threadIdx.x;
    __shared__ int s_slot[K_N];
    __shared__ float s_w[K_N];
    if (tid < K_N) {
        s_slot[tid] = pair_slot[t * K_N + tid];
        s_w[tid] = probs[t * K_N + tid];
    }
    __syncthreads();
    float4 acc = *(float4*)(out + (long)t * H_N + (tid << 2));
    #pragma unroll
    for (int k = 0; k < K_N; ++k) {
        int slot = s_slot[k];
        if (slot >= 0) {
            float wgt = s_w[k];
            ushort4 v = *(const ushort4*)(y + (long)slot * H_N + (tid << 2));
            acc.x = fmaf(wgt, bf2f(v.x), acc.x);
            acc.y = fmaf(wgt, bf2f(v.y), acc.y);
            acc.z = fmaf(wgt, bf2f(v.z), acc.z);
            acc.w = fmaf(wgt, bf2f(v.w), acc.w);
        }
    }
    *(float4*)(out + (long)t * H_N + (tid << 2)) = acc;
}

extern "C" void kernel_launch(void* const* d_in, const int* in_sizes, int n_in,
                              void* d_out, int out_size, void* d_ws, size_t ws_size,
                              hipStream_t stream) {
    const float* x    = (const float*)d_in[0];
    const float* rw   = (const float*)d_in[1];
    const float* bias = (const float*)d_in[2];
    const float* w1   = (const float*)d_in[3];
    const float* w2   = (const float*)d_in[4];
    const float* sw1  = (const float*)d_in[5];
    const float* sw2  = (const float*)d_in[6];
    float* out = (float*)d_out;
    char* ws = (char*)d_ws;

    int*            top_idx   = (int*)(ws + 0);
    float*          probs     = (float*)(ws + 49152);
    int*            pair_slot = (int*)(ws + 98304);
    int*            counts    = (int*)(ws + 147456);
    int*            tok       = (int*)(ws + 147712);
    unsigned short* xb        = (unsigned short*)(ws + 246016);    // T*H bf16
    unsigned short* sw1b      = (unsigned short*)(ws + 4440320);   // SF*H  ([N][K])
    unsigned short* sw2b      = (unsigned short*)(ws + 8634624);   // H*SF  ([N][K])
    unsigned short* w1t       = (unsigned short*)(ws + 12828928);  // E*F*H ([N][K])
    unsigned short* w2t       = (unsigned short*)(ws + 79937792);  // E*H*F ([N][K])
    unsigned short* smid      = (unsigned short*)(ws + 147046656); // T*SF bf16
    unsigned short* hmid      = (unsigned short*)(ws + 155435264); // E*CAP*F bf16
    unsigned short* yb        = (unsigned short*)(ws + 180601088); // E*CAP*H bf16

    router_kernel<<<T_N, 64, 0, stream>>>(x, rw, bias, top_idx, probs);
    dispatch_kernel<<<E_N, 256, 0, stream>>>(top_idx, pair_slot, counts, tok);

    cvt_all<<<6144, 256, 0, stream>>>(x, xb, sw1, sw1b, sw2, sw2b);
    transpose_cvt2<<<8192, 256, 0, stream>>>(w1, w1t, w2, w2t);

    gemmA<<<768 + 256, 256, 0, stream>>>(xb, w1t, hmid, sw1b, smid, tok, counts);
    gemmB<<<1536 + 128, 256, 0, stream>>>(hmid, w2t, yb, smid, sw2b, out, counts);

    combine_kernel<<<T_N, 256, 0, stream>>>(yb, pair_slot, probs, out);
}